// Round 1
// baseline (268.588 us; speedup 1.0000x reference)
//
#include <hip/hip_runtime.h>
#include <hip/hip_bf16.h>

typedef __attribute__((ext_vector_type(4))) float f32x4;
typedef __attribute__((ext_vector_type(8))) short short8;

constexpr int Mdim = 32768;   // 8*4096
constexpr int Kdim = 1024;
constexpr int Ndim = 1024;
constexpr float FEPS = 1e-8f;

// ---------------- ws layout (bytes) ----------------
// 0      : unsigned absmax bits
// 256    : float partials[64]
// 1024   : float scalars[8]  {gamma_w, gamma_b, scale, sg, qs, inv_scale}
// 4096   : float bq[1024]
// 8192   : ushort wq[1024*1024]        (2 MB, ternary as bf16 bits)
// 2105344: ushort xq[32768*1024]       (64 MB, int-valued bf16 bits)
constexpr size_t WQ_OFF = 8192;
constexpr size_t XQ_OFF = 8192 + (size_t)Ndim * Kdim * 2;
constexpr size_t WS_NEED = XQ_OFF + (size_t)Mdim * Kdim * 2;

__device__ __forceinline__ void gload16(const void* g, void* l) {
  __builtin_amdgcn_global_load_lds(
      (const __attribute__((address_space(1))) unsigned int*)g,
      (__attribute__((address_space(3))) unsigned int*)l, 16, 0, 0);
}

// ---------------- pass 1: |x| absmax (deterministic: atomicMax on uint bits) ----
__global__ void k_absmax(const uint4* __restrict__ xv, unsigned* __restrict__ absptr, int n4) {
  int i0 = blockIdx.x * blockDim.x + threadIdx.x;
  int stride = gridDim.x * blockDim.x;
  unsigned m = 0u;
  for (int i = i0; i < n4; i += stride) {
    uint4 v = xv[i];
    m = max(m, v.x & 0x7fffffffu);
    m = max(m, v.y & 0x7fffffffu);
    m = max(m, v.z & 0x7fffffffu);
    m = max(m, v.w & 0x7fffffffu);
  }
  #pragma unroll
  for (int off = 32; off > 0; off >>= 1)
    m = max(m, (unsigned)__shfl_down((int)m, off, 64));
  if ((threadIdx.x & 63) == 0) atomicMax(absptr, m);
}

// ---------------- pass 2: per-block partial sums of |W| (fixed slots) ----------
__global__ void k_wsum(const float* __restrict__ w, float* __restrict__ partials, int n) {
  float s = 0.f;
  int stride = gridDim.x * blockDim.x;
  for (int i = blockIdx.x * blockDim.x + threadIdx.x; i < n; i += stride)
    s += fabsf(w[i]);
  __shared__ float red[256];
  red[threadIdx.x] = s;
  __syncthreads();
  for (int h = 128; h > 0; h >>= 1) {
    if (threadIdx.x < h) red[threadIdx.x] += red[threadIdx.x + h];
    __syncthreads();
  }
  if (threadIdx.x == 0) partials[blockIdx.x] = red[0];
}

// ---------------- pass 3: scalars + quantized bias --------------------------
__global__ void k_finalize(const float* __restrict__ bias, const float* __restrict__ partials,
                           const unsigned* __restrict__ absptr,
                           float* __restrict__ scalars, float* __restrict__ bq) {
  __shared__ float red[256];
  __shared__ float sh_gb;
  int t = threadIdx.x;
  float s = fabsf(bias[t]) + fabsf(bias[t + 256]) + fabsf(bias[t + 512]) + fabsf(bias[t + 768]);
  red[t] = s;
  __syncthreads();
  for (int h = 128; h > 0; h >>= 1) {
    if (t < h) red[t] += red[t + h];
    __syncthreads();
  }
  if (t == 0) {
    float gb = red[0] / 1024.0f;
    float sw = 0.f;
    for (int i = 0; i < 64; ++i) sw += partials[i];
    float gw = sw / (1024.0f * 1024.0f);
    float maxval = __uint_as_float(*absptr);
    // scale = exp2(floor(log2(max/127 + eps))) ; exact floor-log2 via exponent bits
    float v = maxval / 127.0f + FEPS;
    int e = (int)((__float_as_uint(v) >> 23) & 0xff) - 127;
    float scale = ldexpf(1.0f, e);
    scalars[0] = gw;
    scalars[1] = gb;
    scalars[2] = scale;
    scalars[3] = scale * gw;      // sg: epilogue multiplier
    scalars[4] = 127.0f * scale;  // qs: clip bound (exact)
    scalars[5] = ldexpf(1.0f, -e);// inv_scale (exact power of 2)
    sh_gb = gb;
  }
  __syncthreads();
  float gb = sh_gb;
  for (int i = t; i < 1024; i += 256) {
    float q = rintf(bias[i] / (gb + FEPS));
    q = fminf(fmaxf(q, -1.0f), 1.0f);
    bq[i] = q * gb;
  }
}

// ---------------- pass 4: ternary-quantize W to bf16 bits -------------------
__global__ void k_wquant(const float* __restrict__ w, const float* __restrict__ scalars,
                         ushort* __restrict__ wq, int n) {
  float gw = scalars[0];
  float inv_g = gw + FEPS;
  int stride = gridDim.x * blockDim.x;
  for (int i = blockIdx.x * blockDim.x + threadIdx.x; i < n; i += stride) {
    float q = rintf(w[i] / inv_g);
    q = fminf(fmaxf(q, -1.0f), 1.0f);
    wq[i] = (ushort)(__float_as_uint(q) >> 16);  // exact for {-1,0,1}
  }
}

// ---------------- pass 5: quantize x to integer-valued bf16 bits -------------
__device__ __forceinline__ ushort qact(float v, float qs, float inv) {
  float t = rintf(fminf(fmaxf(v, -qs), qs) * inv);  // integer in [-127,127]
  return (ushort)(__float_as_uint(t) >> 16);        // exact (|int| <= 255)
}

__global__ void k_xquant(const float4* __restrict__ xv, const float* __restrict__ scalars,
                         uint4* __restrict__ xqv, int n8) {
  float qs = scalars[4], inv = scalars[5];
  int i0 = blockIdx.x * blockDim.x + threadIdx.x;
  int stride = gridDim.x * blockDim.x;
  for (int i = i0; i < n8; i += stride) {
    float4 a = xv[2 * i];
    float4 b = xv[2 * i + 1];
    unsigned r0 = (unsigned)qact(a.x, qs, inv) | ((unsigned)qact(a.y, qs, inv) << 16);
    unsigned r1 = (unsigned)qact(a.z, qs, inv) | ((unsigned)qact(a.w, qs, inv) << 16);
    unsigned r2 = (unsigned)qact(b.x, qs, inv) | ((unsigned)qact(b.y, qs, inv) << 16);
    unsigned r3 = (unsigned)qact(b.z, qs, inv) | ((unsigned)qact(b.w, qs, inv) << 16);
    uint4 o; o.x = r0; o.y = r1; o.z = r2; o.w = r3;
    xqv[i] = o;
  }
}

// ---------------- pass 6: bf16 MFMA GEMM (m97 structure) --------------------
// C[m][n] = (sum_k xint[m][k]*t[n][k]) * sg + bq[n]
// 128x128 tile, BK=32, 256 threads (4 waves), each wave 64x64 (4x4 frags of 16x16x32)
__launch_bounds__(256)
__global__ void k_gemm(const ushort* __restrict__ xq, const ushort* __restrict__ wq,
                       const float* __restrict__ scalars, const float* __restrict__ bq,
                       float* __restrict__ out) {
  __shared__ __align__(16) ushort As[128 * 32];
  __shared__ __align__(16) ushort Bs[128 * 32];

  const int tid = threadIdx.x;
  const int lane = tid & 63;
  const int wv = tid >> 6;          // 0..3
  const int wr = wv >> 1;           // wave row 0..1
  const int wc = wv & 1;            // wave col 0..1

  // XCD-aware swizzle (2048 % 8 == 0 -> bijective)
  int bid = blockIdx.x;
  int swz = (bid & 7) * ((int)gridDim.x >> 3) + (bid >> 3);
  const int mtile = swz >> 3;       // 0..255
  const int ntile = swz & 7;        // 0..7
  const int m0 = mtile * 128;
  const int n0 = ntile * 128;

  f32x4 acc[4][4];
  #pragma unroll
  for (int i = 0; i < 4; ++i)
    #pragma unroll
    for (int j = 0; j < 4; ++j)
      acc[i][j] = (f32x4){0.f, 0.f, 0.f, 0.f};

  // staging: per wave 2 issues for A + 2 for B; each issue = 16 rows x 32 cols
  const ushort* gA0 = xq + (size_t)(m0 + wv * 32 + (lane >> 2)) * Kdim + (lane & 3) * 8;
  const ushort* gB0 = wq + (size_t)(n0 + wv * 32 + (lane >> 2)) * Kdim + (lane & 3) * 8;
  ushort* lA0 = As + wv * 2 * 512;  // 512 elems = 16 rows * 32 cols
  ushort* lA1 = As + (wv * 2 + 1) * 512;
  ushort* lB0 = Bs + wv * 2 * 512;
  ushort* lB1 = Bs + (wv * 2 + 1) * 512;

  const int fr = lane & 15;         // row within 16-block
  const int fc = (lane >> 4) * 8;   // k-chunk

#define STAGE(kt) do {                              \
    const ushort* ga = gA0 + (kt) * 32;             \
    gload16(ga, lA0);                               \
    gload16(ga + 16 * Kdim, lA1);                   \
    const ushort* gb = gB0 + (kt) * 32;             \
    gload16(gb, lB0);                               \
    gload16(gb + 16 * Kdim, lB1);                   \
  } while (0)

  STAGE(0);

  for (int kt = 0; kt < Kdim / 32; ++kt) {
    __syncthreads();   // staging of tile kt complete (vmcnt(0) before barrier)
    short8 a[4], b[4];
    #pragma unroll
    for (int mi = 0; mi < 4; ++mi)
      a[mi] = *(const short8*)(As + (wr * 64 + mi * 16 + fr) * 32 + fc);
    #pragma unroll
    for (int ni = 0; ni < 4; ++ni)
      b[ni] = *(const short8*)(Bs + (wc * 64 + ni * 16 + fr) * 32 + fc);
    #pragma unroll
    for (int mi = 0; mi < 4; ++mi)
      #pragma unroll
      for (int ni = 0; ni < 4; ++ni)
        acc[mi][ni] = __builtin_amdgcn_mfma_f32_16x16x32_bf16(a[mi], b[ni], acc[mi][ni], 0, 0, 0);
    __syncthreads();   // LDS reads done, safe to overwrite
    if (kt + 1 < Kdim / 32) STAGE(kt + 1);
  }
#undef STAGE

  // epilogue
  const float sg = scalars[3];
  #pragma unroll
  for (int ni = 0; ni < 4; ++ni) {
    const int col = n0 + wc * 64 + ni * 16 + fr;
    const float bb = bq[col];
    #pragma unroll
    for (int mi = 0; mi < 4; ++mi) {
      const int rowb = m0 + wr * 64 + mi * 16 + (lane >> 4) * 4;
      #pragma unroll
      for (int r = 0; r < 4; ++r)
        out[(size_t)(rowb + r) * Ndim + col] = acc[mi][ni][r] * sg + bb;
    }
  }
}

extern "C" void kernel_launch(void* const* d_in, const int* in_sizes, int n_in,
                              void* d_out, int out_size, void* d_ws, size_t ws_size,
                              hipStream_t stream) {
  const float* x = (const float*)d_in[0];
  const float* weight = (const float*)d_in[1];
  const float* bias = (const float*)d_in[2];
  float* out = (float*)d_out;

  if (ws_size < WS_NEED) return;  // cannot run safely; fail loudly via wrong output

  char* ws = (char*)d_ws;
  unsigned* absptr = (unsigned*)ws;
  float* partials = (float*)(ws + 256);
  float* scalars = (float*)(ws + 1024);
  float* bq = (float*)(ws + 4096);
  ushort* wq = (ushort*)(ws + WQ_OFF);
  ushort* xq = (ushort*)(ws + XQ_OFF);

  hipMemsetAsync(d_ws, 0, 4096, stream);
  k_absmax<<<2048, 256, 0, stream>>>((const uint4*)x, absptr, Mdim * Kdim / 4);
  k_wsum<<<64, 256, 0, stream>>>(weight, partials, Ndim * Kdim);
  k_finalize<<<1, 256, 0, stream>>>(bias, partials, absptr, scalars, bq);
  k_wquant<<<512, 256, 0, stream>>>(weight, scalars, wq, Ndim * Kdim);
  k_xquant<<<2048, 256, 0, stream>>>((const float4*)x, scalars, (uint4*)xq, Mdim * Kdim / 8);
  k_gemm<<<2048, 256, 0, stream>>>(xq, wq, scalars, bq, out);
}

// Round 2
// 117.565 us; speedup vs baseline: 2.2846x; 2.2846x over previous
//
#include <hip/hip_runtime.h>

typedef __attribute__((ext_vector_type(4))) int int4v;

constexpr int Mdim = 32768;   // 8*4096
constexpr int Kdim = 1024;
constexpr int Ndim = 1024;
constexpr float FEPS = 1e-8f;

// ---------------- ws layout (bytes) ----------------
// 0      : float scalars[8]  {gamma_w, gamma_b, scale, sg, qs, inv_scale}
// 1024   : float partials[256]   (|W| partial sums)
// 4096   : unsigned pmax[2048]   (per-block |x| max bits)
// 16384  : float bq[1024]
// 32768  : int8 wq[1024*1024]      (1 MB, ternary)
// 32768+1M : int8 xq[32768*1024]   (32 MB, ints in [-127,127])
constexpr size_t WQ_OFF = 32768;
constexpr size_t XQ_OFF = WQ_OFF + (size_t)Ndim * Kdim;
constexpr size_t WS_NEED = XQ_OFF + (size_t)Mdim * Kdim;

__device__ __forceinline__ void gload16(const void* g, void* l) {
  __builtin_amdgcn_global_load_lds(
      (const __attribute__((address_space(1))) unsigned int*)g,
      (__attribute__((address_space(3))) unsigned int*)l, 16, 0, 0);
}

// ---------------- pass 1: |x| absmax -> per-block slot (no atomics) ----------
__global__ void k_absmax(const uint4* __restrict__ xv, unsigned* __restrict__ pmax, int n4) {
  int i0 = blockIdx.x * blockDim.x + threadIdx.x;
  int stride = gridDim.x * blockDim.x;
  unsigned m = 0u;
  for (int i = i0; i < n4; i += stride) {
    uint4 v = xv[i];
    m = max(m, v.x & 0x7fffffffu);
    m = max(m, v.y & 0x7fffffffu);
    m = max(m, v.z & 0x7fffffffu);
    m = max(m, v.w & 0x7fffffffu);
  }
  #pragma unroll
  for (int off = 32; off > 0; off >>= 1)
    m = max(m, (unsigned)__shfl_down((int)m, off, 64));
  __shared__ unsigned red[4];
  if ((threadIdx.x & 63) == 0) red[threadIdx.x >> 6] = m;
  __syncthreads();
  if (threadIdx.x == 0) {
    unsigned r = max(max(red[0], red[1]), max(red[2], red[3]));
    pmax[blockIdx.x] = r;   // plain store, fixed slot: deterministic
  }
}

// ---------------- pass 2: per-block partial sums of |W| (fixed slots) --------
__global__ void k_wsum(const float4* __restrict__ wv, float* __restrict__ partials, int n4) {
  float s = 0.f;
  int stride = gridDim.x * blockDim.x;
  for (int i = blockIdx.x * blockDim.x + threadIdx.x; i < n4; i += stride) {
    float4 v = wv[i];
    s += fabsf(v.x) + fabsf(v.y) + fabsf(v.z) + fabsf(v.w);
  }
  __shared__ float red[256];
  red[threadIdx.x] = s;
  __syncthreads();
  for (int h = 128; h > 0; h >>= 1) {
    if (threadIdx.x < h) red[threadIdx.x] += red[threadIdx.x + h];
    __syncthreads();
  }
  if (threadIdx.x == 0) partials[blockIdx.x] = red[0];
}

// ---------------- pass 3: scalars + quantized bias --------------------------
__global__ void k_finalize(const float* __restrict__ bias, const float* __restrict__ partials,
                           const unsigned* __restrict__ pmax,
                           float* __restrict__ scalars, float* __restrict__ bq) {
  __shared__ float redf[256];
  __shared__ unsigned redu[256];
  __shared__ float sh_gb;
  int t = threadIdx.x;

  // bias |.| sum
  float s = fabsf(bias[t]) + fabsf(bias[t + 256]) + fabsf(bias[t + 512]) + fabsf(bias[t + 768]);
  redf[t] = s;
  // pmax reduce (2048 slots)
  unsigned m = 0u;
  #pragma unroll
  for (int i = 0; i < 8; ++i) m = max(m, pmax[t + 256 * i]);
  redu[t] = m;
  __syncthreads();
  for (int h = 128; h > 0; h >>= 1) {
    if (t < h) {
      redf[t] += redf[t + h];
      redu[t] = max(redu[t], redu[t + h]);
    }
    __syncthreads();
  }
  if (t == 0) {
    float gb = redf[0] / 1024.0f;
    float sw = 0.f;
    for (int i = 0; i < 256; ++i) sw += partials[i];
    float gw = sw / (1024.0f * 1024.0f);
    float maxval = __uint_as_float(redu[0]);
    // scale = exp2(floor(log2(max/127 + eps))) ; exact floor-log2 via exponent bits
    float v = maxval / 127.0f + FEPS;
    int e = (int)((__float_as_uint(v) >> 23) & 0xff) - 127;
    float scale = ldexpf(1.0f, e);
    scalars[0] = gw;
    scalars[1] = gb;
    scalars[2] = scale;
    scalars[3] = scale * gw;       // epilogue multiplier
    scalars[4] = 127.0f * scale;   // clip bound (exact)
    scalars[5] = ldexpf(1.0f, -e); // inv_scale (exact power of 2)
    sh_gb = gb;
  }
  __syncthreads();
  float gb = sh_gb;
  for (int i = t; i < 1024; i += 256) {
    float q = rintf(bias[i] / (gb + FEPS));
    q = fminf(fmaxf(q, -1.0f), 1.0f);
    bq[i] = q * gb;
  }
}

// ---------------- pass 4: ternary-quantize W to int8 ------------------------
__global__ void k_wquant(const float4* __restrict__ wv, const float* __restrict__ scalars,
                         unsigned* __restrict__ wq, int n4) {
  float inv_g = scalars[0] + FEPS;
  int i0 = blockIdx.x * blockDim.x + threadIdx.x;
  int stride = gridDim.x * blockDim.x;
  for (int i = i0; i < n4; i += stride) {
    float4 v = wv[i];
    int a = (int)rintf(fminf(fmaxf(v.x / inv_g, -1.f), 1.f));
    int b = (int)rintf(fminf(fmaxf(v.y / inv_g, -1.f), 1.f));
    int c = (int)rintf(fminf(fmaxf(v.z / inv_g, -1.f), 1.f));
    int d = (int)rintf(fminf(fmaxf(v.w / inv_g, -1.f), 1.f));
    wq[i] = (unsigned)(a & 0xff) | ((unsigned)(b & 0xff) << 8) |
            ((unsigned)(c & 0xff) << 16) | ((unsigned)(d & 0xff) << 24);
  }
}

// ---------------- pass 5: quantize x to int8 --------------------------------
__device__ __forceinline__ int qact8(float v, float qs, float inv) {
  return (int)rintf(fminf(fmaxf(v, -qs), qs) * inv);  // in [-127,127]
}

__device__ __forceinline__ unsigned pack4(float4 a, float qs, float inv) {
  return (unsigned)(qact8(a.x, qs, inv) & 0xff) |
         ((unsigned)(qact8(a.y, qs, inv) & 0xff) << 8) |
         ((unsigned)(qact8(a.z, qs, inv) & 0xff) << 16) |
         ((unsigned)(qact8(a.w, qs, inv) & 0xff) << 24);
}

__global__ void k_xquant(const float4* __restrict__ xv, const float* __restrict__ scalars,
                         uint4* __restrict__ xqv, int n16) {
  float qs = scalars[4], inv = scalars[5];
  int i0 = blockIdx.x * blockDim.x + threadIdx.x;
  int stride = gridDim.x * blockDim.x;
  for (int i = i0; i < n16; i += stride) {
    float4 a = xv[4 * i + 0];
    float4 b = xv[4 * i + 1];
    float4 c = xv[4 * i + 2];
    float4 d = xv[4 * i + 3];
    uint4 o;
    o.x = pack4(a, qs, inv);
    o.y = pack4(b, qs, inv);
    o.z = pack4(c, qs, inv);
    o.w = pack4(d, qs, inv);
    xqv[i] = o;
  }
}

// ---------------- pass 6: int8 MFMA GEMM (m97 structure, BK=64) -------------
// C[m][n] = (sum_k xint[m][k]*t[n][k]) * sg + bq[n]   (i32 accum, exact)
// 128x128 tile, BK=64 i8 (64 B/row), 256 threads (4 waves), wave = 64x64
__launch_bounds__(256)
__global__ void k_gemm(const unsigned char* __restrict__ xq, const unsigned char* __restrict__ wq,
                       const float* __restrict__ scalars, const float* __restrict__ bq,
                       float* __restrict__ out) {
  __shared__ __align__(16) unsigned char As[128 * 64];
  __shared__ __align__(16) unsigned char Bs[128 * 64];

  const int tid = threadIdx.x;
  const int lane = tid & 63;
  const int wv = tid >> 6;          // 0..3
  const int wr = wv >> 1;           // wave row 0..1
  const int wc = wv & 1;            // wave col 0..1

  // XCD-aware swizzle (2048 % 8 == 0 -> bijective)
  int bid = blockIdx.x;
  int swz = (bid & 7) * ((int)gridDim.x >> 3) + (bid >> 3);
  const int mtile = swz >> 3;       // 0..255
  const int ntile = swz & 7;        // 0..7
  const int m0 = mtile * 128;
  const int n0 = ntile * 128;

  int4v acc[4][4];
  #pragma unroll
  for (int i = 0; i < 4; ++i)
    #pragma unroll
    for (int j = 0; j < 4; ++j)
      acc[i][j] = (int4v){0, 0, 0, 0};

  // staging: per wave 2 issues for A + 2 for B; each issue = 16 rows x 64 B
  const unsigned char* gA0 = xq + (size_t)(m0 + wv * 32 + (lane >> 2)) * Kdim + (lane & 3) * 16;
  const unsigned char* gB0 = wq + (size_t)(n0 + wv * 32 + (lane >> 2)) * Kdim + (lane & 3) * 16;
  unsigned char* lA0 = As + wv * 2048;
  unsigned char* lA1 = As + wv * 2048 + 1024;
  unsigned char* lB0 = Bs + wv * 2048;
  unsigned char* lB1 = Bs + wv * 2048 + 1024;

  const int fr = lane & 15;           // row within 16-block
  const int fc = (lane >> 4) * 16;    // k-chunk byte offset

#define STAGE(kt) do {                              \
    const unsigned char* ga = gA0 + (kt) * 64;      \
    gload16(ga, lA0);                               \
    gload16(ga + 16 * Kdim, lA1);                   \
    const unsigned char* gb = gB0 + (kt) * 64;      \
    gload16(gb, lB0);                               \
    gload16(gb + 16 * Kdim, lB1);                   \
  } while (0)

  STAGE(0);

  for (int kt = 0; kt < Kdim / 64; ++kt) {
    __syncthreads();   // staging of tile kt complete (vmcnt(0) before barrier)
    int4v a[4], b[4];
    #pragma unroll
    for (int mi = 0; mi < 4; ++mi)
      a[mi] = *(const int4v*)(As + (wr * 64 + mi * 16 + fr) * 64 + fc);
    #pragma unroll
    for (int ni = 0; ni < 4; ++ni)
      b[ni] = *(const int4v*)(Bs + (wc * 64 + ni * 16 + fr) * 64 + fc);
    #pragma unroll
    for (int mi = 0; mi < 4; ++mi)
      #pragma unroll
      for (int ni = 0; ni < 4; ++ni)
        acc[mi][ni] = __builtin_amdgcn_mfma_i32_16x16x64_i8(a[mi], b[ni], acc[mi][ni], 0, 0, 0);
    __syncthreads();   // LDS reads done, safe to overwrite
    if (kt + 1 < Kdim / 64) STAGE(kt + 1);
  }
#undef STAGE

  // epilogue: exact i32 -> f32, scale, bias
  const float sg = scalars[3];
  #pragma unroll
  for (int ni = 0; ni < 4; ++ni) {
    const int col = n0 + wc * 64 + ni * 16 + fr;
    const float bb = bq[col];
    #pragma unroll
    for (int mi = 0; mi < 4; ++mi) {
      const int rowb = m0 + wr * 64 + mi * 16 + (lane >> 4) * 4;
      #pragma unroll
      for (int r = 0; r < 4; ++r)
        out[(size_t)(rowb + r) * Ndim + col] = (float)acc[mi][ni][r] * sg + bb;
    }
  }
}

extern "C" void kernel_launch(void* const* d_in, const int* in_sizes, int n_in,
                              void* d_out, int out_size, void* d_ws, size_t ws_size,
                              hipStream_t stream) {
  const float* x = (const float*)d_in[0];
  const float* weight = (const float*)d_in[1];
  const float* bias = (const float*)d_in[2];
  float* out = (float*)d_out;

  if (ws_size < WS_NEED) return;

  char* ws = (char*)d_ws;
  float* scalars = (float*)ws;
  float* partials = (float*)(ws + 1024);
  unsigned* pmax = (unsigned*)(ws + 4096);
  float* bq = (float*)(ws + 16384);
  unsigned char* wq = (unsigned char*)(ws + WQ_OFF);
  unsigned char* xq = (unsigned char*)(ws + XQ_OFF);

  k_absmax<<<2048, 256, 0, stream>>>((const uint4*)x, pmax, Mdim * Kdim / 4);
  k_wsum<<<256, 256, 0, stream>>>((const float4*)weight, partials, Ndim * Kdim / 4);
  k_finalize<<<1, 256, 0, stream>>>(bias, partials, pmax, scalars, bq);
  k_wquant<<<512, 256, 0, stream>>>((const float4*)weight, scalars, (unsigned*)wq, Ndim * Kdim / 4);
  k_xquant<<<2048, 256, 0, stream>>>((const float4*)x, scalars, (uint4*)xq, Mdim * Kdim / 16);
  k_gemm<<<2048, 256, 0, stream>>>(xq, wq, scalars, bq, out);
}